// Round 1
// baseline (330.572 us; speedup 1.0000x reference)
//
#include <hip/hip_runtime.h>

// Problem constants
#define B_ 2
#define N_ 196608
#define K_ 9
#define F_ 64

typedef __attribute__((ext_vector_type(8))) short short8;
typedef __attribute__((ext_vector_type(8))) unsigned short ushort8;
typedef __attribute__((ext_vector_type(4))) float f32x4;

__device__ __forceinline__ unsigned short f2bf(float f) {
  unsigned u = __builtin_bit_cast(unsigned, f);
  u = (u + 0x7fffu + ((u >> 16) & 1u)) >> 16;   // RNE
  return (unsigned short)u;
}

// x fp32 [B][N][64] -> bf16 bits, 8 elems/thread
__global__ __launch_bounds__(256) void cvt_x_kernel(const float* __restrict__ x,
                                                    unsigned short* __restrict__ xb) {
  const long i = (long)blockIdx.x * 256 + threadIdx.x;  // one per 8 elements
  const float4 v0 = ((const float4*)x)[2 * i];
  const float4 v1 = ((const float4*)x)[2 * i + 1];
  ushort8 r;
  r[0] = f2bf(v0.x); r[1] = f2bf(v0.y); r[2] = f2bf(v0.z); r[3] = f2bf(v0.w);
  r[4] = f2bf(v1.x); r[5] = f2bf(v1.y); r[6] = f2bf(v1.z); r[7] = f2bf(v1.w);
  ((ushort8*)xb)[i] = r;
}

// W fp32 [9][64][64] (k,f,o) -> Wt bf16 [9][64][64] (k,o,f)
__global__ __launch_bounds__(256) void cvt_w_kernel(const float* __restrict__ W,
                                                    unsigned short* __restrict__ wt) {
  const int i = blockIdx.x * 256 + threadIdx.x;  // i = k*4096 + o*64 + f
  const int k = i >> 12;
  const int rem = i & 4095;
  const int o = rem >> 6;
  const int f = rem & 63;
  wt[i] = f2bf(W[(k << 12) + (f << 6) + o]);
}

// Main: block = 256 thr (4 waves); tile = 128 rows x 64 cols.
// Wave w: rows w*32 .. w*32+31 (2 subtiles of 16), all 64 cols (4 col-tiles).
__global__ __launch_bounds__(256) void nhconv_main(
    const short* __restrict__ xb,    // [B][N][64] bf16 bits
    const int* __restrict__ adjc,    // [N][9] int32
    const short* __restrict__ wt,    // [9][64][64] bf16 bits, Wt[k][o][f]
    const float* __restrict__ bias,  // [64]
    float* __restrict__ out) {       // [B][N][64] fp32
  const int bb = blockIdx.y;
  const int n0 = blockIdx.x * 128;
  const int tid = (int)threadIdx.x;
  const int w = tid >> 6;          // wave 0..3
  const int l = tid & 63;          // lane
  const int q = l >> 4;            // quad 0..3
  const int c = l & 15;

  // Rows this lane's A-fragments cover (A row m = lane&15)
  const int n_s0 = n0 + w * 32 + c;
  const int n_s1 = n_s0 + 16;

  // Preload neighbor indices for all 9 k
  int g0[K_], g1[K_];
#pragma unroll
  for (int k = 0; k < K_; ++k) {
    g0[k] = adjc[n_s0 * K_ + k];
    g1[k] = adjc[n_s1 * K_ + k];
  }

  const size_t xbase = (size_t)bb * N_ * F_;

  f32x4 acc[2][4];
#pragma unroll
  for (int s = 0; s < 2; ++s)
#pragma unroll
    for (int ct = 0; ct < 4; ++ct)
      acc[s][ct] = (f32x4){0.f, 0.f, 0.f, 0.f};

#pragma unroll
  for (int k = 0; k < K_; ++k) {
    const short* arow0 = xb + xbase + (size_t)g0[k] * F_;
    const short* arow1 = xb + xbase + (size_t)g1[k] * F_;
#pragma unroll
    for (int fs = 0; fs < 2; ++fs) {
      const int fo = fs * 32 + q * 8;  // 16B-aligned offset into 64-elem row
      const short8 a0 = *(const short8*)(arow0 + fo);
      const short8 a1 = *(const short8*)(arow1 + fo);
      const short* wk = wt + (k << 12) + fo;  // + (col)*64 below
#pragma unroll
      for (int ct = 0; ct < 4; ++ct) {
        const short8 bf = *(const short8*)(wk + ((ct * 16 + c) << 6));
        acc[0][ct] = __builtin_amdgcn_mfma_f32_16x16x32_bf16(a0, bf, acc[0][ct], 0, 0, 0);
        acc[1][ct] = __builtin_amdgcn_mfma_f32_16x16x32_bf16(a1, bf, acc[1][ct], 0, 0, 0);
      }
    }
  }

  // Epilogue: C col = lane&15, row = quad*4 + reg
  float bv[4];
#pragma unroll
  for (int ct = 0; ct < 4; ++ct) bv[ct] = bias[ct * 16 + c];

  const size_t outbase = ((size_t)bb * N_ + (size_t)(n0 + w * 32)) * F_;
#pragma unroll
  for (int s = 0; s < 2; ++s) {
#pragma unroll
    for (int ct = 0; ct < 4; ++ct) {
#pragma unroll
      for (int r = 0; r < 4; ++r) {
        const int row = s * 16 + q * 4 + r;
        out[outbase + (size_t)row * F_ + ct * 16 + c] = acc[s][ct][r] + bv[ct];
      }
    }
  }
}

extern "C" void kernel_launch(void* const* d_in, const int* in_sizes, int n_in,
                              void* d_out, int out_size, void* d_ws, size_t ws_size,
                              hipStream_t stream) {
  const float* x = (const float*)d_in[0];
  const int* adjc = (const int*)d_in[1];
  const float* W = (const float*)d_in[2];
  const float* bias = (const float*)d_in[3];
  float* out = (float*)d_out;

  unsigned short* xb = (unsigned short*)d_ws;                    // 50,331,648 B
  unsigned short* wt = (unsigned short*)((char*)d_ws + (size_t)B_ * N_ * F_ * 2);

  // x convert: 25,165,824 elems / 8 per thread / 256 per block = 12288 blocks
  cvt_x_kernel<<<12288, 256, 0, stream>>>(x, xb);
  // W convert+transpose: 36864 elems / 256 = 144 blocks
  cvt_w_kernel<<<144, 256, 0, stream>>>(W, wt);

  dim3 grid(N_ / 128, B_);
  nhconv_main<<<grid, 256, 0, stream>>>((const short*)xb, adjc, (const short*)wt,
                                        bias, out);
}